// Round 1
// baseline (2119.537 us; speedup 1.0000x reference)
//
#include <hip/hip_runtime.h>
#include <cstdint>
#include <cstddef>

// Problem constants
#define B_      16
#define L_      128
#define V_      32000
#define E_      512
#define H_      1024
#define D_      512
#define K_      1024      // E+D == H == 1024 (shared GEMM K)
#define G4_     4096      // 4*H
#define T_      127       // recurrence steps (L-1)
#define M_REAL  2032      // T_*B_
#define M_PAD   2048      // padded to tile multiple

typedef __attribute__((ext_vector_type(8))) short  short8;   // 8 bf16 (4 VGPRs)
typedef __attribute__((ext_vector_type(4))) short  short4v;
typedef __attribute__((ext_vector_type(4))) float  f32x4;

typedef const __attribute__((address_space(1))) void* gas_ptr;
typedef __attribute__((address_space(3))) void*       las_ptr;

__device__ __forceinline__ void gl_lds16(const void* g, void* l) {
    // async global->LDS, 16B/lane, LDS dest = wave-uniform base + lane*16
    __builtin_amdgcn_global_load_lds((gas_ptr)g, (las_ptr)l, 16, 0, 0);
}

__device__ __forceinline__ short f2bf(float f) {
    union { float f; unsigned u; } v; v.f = f;
    unsigned r = (v.u + 0x7FFFu + ((v.u >> 16) & 1u)) >> 16;
    return (short)r;
}

__device__ __forceinline__ float sigm(float x) { return 1.0f / (1.0f + expf(-x)); }

// ---------------------------------------------------------------------------
// init: zero Hall (slot0 = h_{-1} = 0 and tail pad rows) + barrier counters
// ---------------------------------------------------------------------------
__global__ void init_kernel(unsigned* hall_u32, unsigned* bar) {
    const size_t n = (size_t)(M_PAD + 16) * K_ * 2 / 4;
    size_t i = (size_t)blockIdx.x * blockDim.x + threadIdx.x;
    const size_t stride = (size_t)gridDim.x * blockDim.x;
    for (size_t k = i; k < n; k += stride) hall_u32[k] = 0u;
    if (i == 0) { bar[0] = 0u; bar[1] = 0u; }
}

// ---------------------------------------------------------------------------
// fp32 -> bf16 convert, 4 elems/thread
// ---------------------------------------------------------------------------
__global__ void cvt_bf16_kernel(const float* __restrict__ src, short* __restrict__ dst, int n4) {
    int i = blockIdx.x * blockDim.x + threadIdx.x;
    if (i < n4) {
        float4 v = *(const float4*)(src + (size_t)i * 4);
        short4v o = { f2bf(v.x), f2bf(v.y), f2bf(v.z), f2bf(v.w) };
        *(short4v*)(dst + (size_t)i * 4) = o;
    }
}

// ---------------------------------------------------------------------------
// gather X rows: X[m=t*16+b] = bf16([emb[target[b,t]], latent[b]]); pad rows 0
// ---------------------------------------------------------------------------
__global__ void gather_x_kernel(const float* __restrict__ emb, const float* __restrict__ latent,
                                const int* __restrict__ target, short* __restrict__ X) {
    int m = blockIdx.x;          // 0..M_PAD-1
    int e = threadIdx.x * 4;     // 0..1020
    short4v o;
    if (m >= M_REAL) {
        o = (short4v){0, 0, 0, 0};
    } else {
        int t = m >> 4, b = m & 15;
        float4 v;
        if (e < E_) {
            int tok = target[b * L_ + t];
            v = *(const float4*)(emb + (size_t)tok * E_ + e);
        } else {
            v = *(const float4*)(latent + (size_t)b * D_ + (e - E_));
        }
        o = (short4v){ f2bf(v.x), f2bf(v.y), f2bf(v.z), f2bf(v.w) };
    }
    *(short4v*)(X + (size_t)m * K_ + e) = o;
}

// ---------------------------------------------------------------------------
// bf16 MFMA GEMM: C[M,N] = A[M,K] * Bt[N,K]^T  (m97 structure: 128x128 tile,
// BK=32, global_load_lds width16, 2x2 waves x 4x4 16x16x32 frags)
// mode 0: out[m*N+n] = acc + bias1[n] + bias2[n]          (pre-gates)
// mode 1: out[b*L*V + (t+1)*V + n] = acc + bias1[n], m=t*16+b  (logits)
// ---------------------------------------------------------------------------
__global__ __launch_bounds__(256) void gemm_bt_kernel(
    const short* __restrict__ A, const short* __restrict__ Bt,
    float* __restrict__ out, const float* __restrict__ bias1,
    const float* __restrict__ bias2, int M_real, int N, int K, int mode) {
    __shared__ short As[128 * 32];
    __shared__ short Bs[128 * 32];
    const int tid  = threadIdx.x;
    const int w    = tid >> 6;
    const int lane = tid & 63;
    const int quad = lane >> 4;
    const int l16  = lane & 15;
    const int n0   = blockIdx.x * 128;
    const int m0   = blockIdx.y * 128;
    const int wm   = w >> 1, wn = w & 1;

    f32x4 acc[4][4];
#pragma unroll
    for (int i = 0; i < 4; ++i)
#pragma unroll
        for (int j = 0; j < 4; ++j) acc[i][j] = (f32x4){0.f, 0.f, 0.f, 0.f};

    const int srow = lane >> 2;        // staging row within 16-row segment
    const int skel = (lane & 3) * 8;   // staging k-element offset

    const int s0 = w, s1 = w + 4;      // this wave's two LDS segments
    for (int kk = 0; kk < K; kk += 32) {
        gl_lds16(A  + (size_t)(m0 + s0 * 16 + srow) * K + kk + skel, As + s0 * 512);
        gl_lds16(A  + (size_t)(m0 + s1 * 16 + srow) * K + kk + skel, As + s1 * 512);
        gl_lds16(Bt + (size_t)(n0 + s0 * 16 + srow) * K + kk + skel, Bs + s0 * 512);
        gl_lds16(Bt + (size_t)(n0 + s1 * 16 + srow) * K + kk + skel, Bs + s1 * 512);
        __syncthreads();
        short8 af[4], bf[4];
#pragma unroll
        for (int i = 0; i < 4; ++i)
            af[i] = *(const short8*)(As + (wm * 64 + i * 16 + l16) * 32 + quad * 8);
#pragma unroll
        for (int j = 0; j < 4; ++j)
            bf[j] = *(const short8*)(Bs + (wn * 64 + j * 16 + l16) * 32 + quad * 8);
#pragma unroll
        for (int i = 0; i < 4; ++i)
#pragma unroll
            for (int j = 0; j < 4; ++j)
                acc[i][j] = __builtin_amdgcn_mfma_f32_16x16x32_bf16(af[i], bf[j], acc[i][j], 0, 0, 0);
        __syncthreads();
    }

#pragma unroll
    for (int i = 0; i < 4; ++i) {
#pragma unroll
        for (int j = 0; j < 4; ++j) {
            const int mbase = m0 + wm * 64 + i * 16 + quad * 4;
            const int n     = n0 + wn * 64 + j * 16 + l16;
#pragma unroll
            for (int r = 0; r < 4; ++r) {
                const int m = mbase + r;
                if (m < M_real) {
                    float v = acc[i][j][r];
                    if (mode == 0) {
                        out[(size_t)m * N + n] = v + bias1[n] + bias2[n];
                    } else {
                        const int t = m >> 4, b = m & 15;
                        out[(size_t)b * ((size_t)L_ * V_) + (size_t)(t + 1) * V_ + n] = v + bias1[n];
                    }
                }
            }
        }
    }
}

// ---------------------------------------------------------------------------
// persistent LSTM recurrence: 64 blocks x 256 thr. Block p owns h-cols
// [p*16, p*16+16). Wave w computes gate w's 16x16 tile (K=1024) with its
// W_hh slice preloaded into 128 VGPRs. One grid barrier per step; h_t stored
// into Hall slot t+1 (slot 0 = zeros) => natural double buffering.
// ---------------------------------------------------------------------------
__global__ __launch_bounds__(256) void lstm_recur_kernel(
    const short* __restrict__ Whh,   // bf16 (4096 x 1024) row-major
    const float* __restrict__ xg,    // (M_PAD x 4096) fp32 precomputed gates
    short* __restrict__ Hall,        // bf16 (M_PAD+16 x 1024); row s*16+b = h_{s-1}[b]
    unsigned* bar) {
    __shared__ float gl[1024];
    const int tid  = threadIdx.x;
    const int w    = tid >> 6;
    const int lane = tid & 63;
    const int quad = lane >> 4;
    const int l16  = lane & 15;
    const int p    = blockIdx.x;     // 0..63

    // preload W_hh fragments: wave w, gate w, rows w*1024 + p*16 + l16
    const short* Brow = Whh + (size_t)(w * H_ + p * 16 + l16) * K_ + quad * 8;
    short8 breg[32];
#pragma unroll
    for (int ks = 0; ks < 32; ++ks) breg[ks] = *(const short8*)(Brow + ks * 32);

    const int b  = tid >> 4;   // epilogue mapping: thread owns (b, jc)
    const int jc = tid & 15;
    float c = 0.0f;
    unsigned* cnt = bar;
    unsigned* gen = bar + 1;

    for (int t = 0; t < T_; ++t) {
        const short* Arow = Hall + (size_t)(t * 16 + l16) * K_ + quad * 8;
        f32x4 a0 = (f32x4){0.f,0.f,0.f,0.f}, a1 = a0, a2 = a0, a3 = a0;
#pragma unroll
        for (int ks = 0; ks < 32; ks += 4) {
            short8 f0 = *(const short8*)(Arow + (ks + 0) * 32);
            short8 f1 = *(const short8*)(Arow + (ks + 1) * 32);
            short8 f2 = *(const short8*)(Arow + (ks + 2) * 32);
            short8 f3 = *(const short8*)(Arow + (ks + 3) * 32);
            a0 = __builtin_amdgcn_mfma_f32_16x16x32_bf16(f0, breg[ks + 0], a0, 0, 0, 0);
            a1 = __builtin_amdgcn_mfma_f32_16x16x32_bf16(f1, breg[ks + 1], a1, 0, 0, 0);
            a2 = __builtin_amdgcn_mfma_f32_16x16x32_bf16(f2, breg[ks + 2], a2, 0, 0, 0);
            a3 = __builtin_amdgcn_mfma_f32_16x16x32_bf16(f3, breg[ks + 3], a3, 0, 0, 0);
        }
        f32x4 g = (a0 + a1) + (a2 + a3);
#pragma unroll
        for (int r = 0; r < 4; ++r) gl[w * 256 + (quad * 4 + r) * 16 + l16] = g[r];
        __syncthreads();

        const float* xgp = xg + (size_t)(t * 16 + b) * G4_ + p * 16 + jc;
        float gi = gl[tid]       + xgp[0];
        float gf = gl[256 + tid] + xgp[1024];
        float gg = gl[512 + tid] + xgp[2048];
        float go = gl[768 + tid] + xgp[3072];
        float iv = sigm(gi), fv = sigm(gf), gv = tanhf(gg), ov = sigm(go);
        c = fv * c + iv * gv;
        float h = ov * tanhf(c);
        Hall[(size_t)((t + 1) * 16 + b) * K_ + p * 16 + jc] = f2bf(h);

        // grid barrier (device-scope, sense via generation counter)
        __syncthreads();
        if (tid == 0) {
            __threadfence();
            unsigned gcur = __hip_atomic_load(gen, __ATOMIC_RELAXED, __HIP_MEMORY_SCOPE_AGENT);
            unsigned a = __hip_atomic_fetch_add(cnt, 1u, __ATOMIC_ACQ_REL, __HIP_MEMORY_SCOPE_AGENT);
            if (a == 63u) {
                __hip_atomic_store(cnt, 0u, __ATOMIC_RELAXED, __HIP_MEMORY_SCOPE_AGENT);
                __hip_atomic_store(gen, gcur + 1u, __ATOMIC_RELEASE, __HIP_MEMORY_SCOPE_AGENT);
            } else {
                while (__hip_atomic_load(gen, __ATOMIC_ACQUIRE, __HIP_MEMORY_SCOPE_AGENT) == gcur) {
                    __builtin_amdgcn_s_sleep(1);
                }
            }
            __threadfence();
        }
        __syncthreads();
    }
}

// ---------------------------------------------------------------------------
// zero out[:, 0, :]
// ---------------------------------------------------------------------------
__global__ void zero_t0_kernel(float* __restrict__ out) {
    int i = blockIdx.x * blockDim.x + threadIdx.x;
    if (i < B_ * V_) {
        int b = i / V_, v = i - b * V_;
        out[(size_t)b * ((size_t)L_ * V_) + v] = 0.f;
    }
}

extern "C" void kernel_launch(void* const* d_in, const int* in_sizes, int n_in,
                              void* d_out, int out_size, void* d_ws, size_t ws_size,
                              hipStream_t stream) {
    const float* latent = (const float*)d_in[0];
    const float* emb    = (const float*)d_in[1];
    const float* W_ih   = (const float*)d_in[2];
    const float* W_hh   = (const float*)d_in[3];
    const float* b_ih   = (const float*)d_in[4];
    const float* b_hh   = (const float*)d_in[5];
    const float* fc_w   = (const float*)d_in[6];
    const float* fc_b   = (const float*)d_in[7];
    const int*   target = (const int*)d_in[8];
    float* out = (float*)d_out;

    char* ws = (char*)d_ws;
    unsigned* bar = (unsigned*)ws;
    size_t off = 256;
    short* Wih_b = (short*)(ws + off); off += (size_t)G4_ * K_ * 2;          // 8 MB
    short* Whh_b = (short*)(ws + off); off += (size_t)G4_ * K_ * 2;          // 8 MB
    short* fcw_b = (short*)(ws + off); off += (size_t)V_ * K_ * 2;           // 62.5 MB
    short* X_b   = (short*)(ws + off); off += (size_t)M_PAD * K_ * 2;        // 4 MB
    short* Hall  = (short*)(ws + off); off += (size_t)(M_PAD + 16) * K_ * 2; // 4 MB
    float* xg    = (float*)(ws + off); off += (size_t)M_PAD * G4_ * 4;       // 32 MB
    (void)ws_size; (void)in_sizes; (void)n_in; (void)out_size;

    // 0) init Hall zeros + barrier
    init_kernel<<<512, 256, 0, stream>>>((unsigned*)Hall, bar);
    // 1) weight converts fp32->bf16
    cvt_bf16_kernel<<<(G4_ * K_ / 4 + 255) / 256, 256, 0, stream>>>(W_ih, Wih_b, G4_ * K_ / 4);
    cvt_bf16_kernel<<<(G4_ * K_ / 4 + 255) / 256, 256, 0, stream>>>(W_hh, Whh_b, G4_ * K_ / 4);
    cvt_bf16_kernel<<<(V_ * K_ / 4 + 255) / 256, 256, 0, stream>>>(fc_w, fcw_b, V_ * K_ / 4);
    // 2) gather X = [emb[tok], latent] in bf16
    gather_x_kernel<<<M_PAD, 256, 0, stream>>>(emb, latent, target, X_b);
    // 3) pre-gates: xg = X @ W_ih^T + (b_ih + b_hh)
    gemm_bt_kernel<<<dim3(G4_ / 128, M_PAD / 128), 256, 0, stream>>>(
        X_b, Wih_b, xg, b_ih, b_hh, M_PAD, G4_, K_, 0);
    // 4) recurrence (persistent, 127 steps)
    lstm_recur_kernel<<<64, 256, 0, stream>>>(Whh_b, xg, Hall, bar);
    // 5) logits = Hall[1..127] @ fc_w^T + fc_b -> out[:, 1:, :]
    gemm_bt_kernel<<<dim3(V_ / 128, M_PAD / 128), 256, 0, stream>>>(
        Hall + (size_t)16 * K_, fcw_b, out, fc_b, nullptr, M_REAL, V_, K_, 1);
    // 6) out[:, 0, :] = 0
    zero_t0_kernel<<<(B_ * V_ + 255) / 256, 256, 0, stream>>>(out);
}

// Round 2
// 1539.597 us; speedup vs baseline: 1.3767x; 1.3767x over previous
//
#include <hip/hip_runtime.h>
#include <cstdint>
#include <cstddef>

// Problem constants
#define B_      16
#define L_      128
#define V_      32000
#define E_      512
#define H_      1024
#define D_      512
#define K_      1024      // E+D == H == 1024 (shared GEMM K)
#define G4_     4096      // 4*H
#define T_      127       // recurrence steps (L-1)
#define M_REAL  2032      // T_*B_
#define M_PAD   2048      // padded to tile multiple

typedef __attribute__((ext_vector_type(8))) short  short8;   // 8 bf16 (4 VGPRs)
typedef __attribute__((ext_vector_type(4))) short  short4v;
typedef __attribute__((ext_vector_type(4))) float  f32x4;

typedef const __attribute__((address_space(1))) void* gas_ptr;
typedef __attribute__((address_space(3))) void*       las_ptr;

__device__ __forceinline__ void gl_lds16(const void* g, void* l) {
    // async global->LDS, 16B/lane, LDS dest = wave-uniform base + lane*16
    __builtin_amdgcn_global_load_lds((gas_ptr)g, (las_ptr)l, 16, 0, 0);
}

__device__ __forceinline__ short f2bf(float f) {
    union { float f; unsigned u; } v; v.f = f;
    unsigned r = (v.u + 0x7FFFu + ((v.u >> 16) & 1u)) >> 16;
    return (short)r;
}

__device__ __forceinline__ float sigm(float x) { return 1.0f / (1.0f + expf(-x)); }

// ---------------------------------------------------------------------------
// init: zero Hall (slot0 = h_{-1} = 0 and tail pad rows) + 64 barrier flags
// ---------------------------------------------------------------------------
__global__ void init_kernel(unsigned* hall_u32, unsigned* flags) {
    const size_t n = (size_t)(M_PAD + 16) * K_ * 2 / 4;
    size_t i = (size_t)blockIdx.x * blockDim.x + threadIdx.x;
    const size_t stride = (size_t)gridDim.x * blockDim.x;
    for (size_t k = i; k < n; k += stride) hall_u32[k] = 0u;
    if (i < 64) flags[i] = 0u;
}

// ---------------------------------------------------------------------------
// fp32 -> bf16 convert, 4 elems/thread
// ---------------------------------------------------------------------------
__global__ void cvt_bf16_kernel(const float* __restrict__ src, short* __restrict__ dst, int n4) {
    int i = blockIdx.x * blockDim.x + threadIdx.x;
    if (i < n4) {
        float4 v = *(const float4*)(src + (size_t)i * 4);
        short4v o = { f2bf(v.x), f2bf(v.y), f2bf(v.z), f2bf(v.w) };
        *(short4v*)(dst + (size_t)i * 4) = o;
    }
}

// ---------------------------------------------------------------------------
// gather X rows: X[m=t*16+b] = bf16([emb[target[b,t]], latent[b]]); pad rows 0
// ---------------------------------------------------------------------------
__global__ void gather_x_kernel(const float* __restrict__ emb, const float* __restrict__ latent,
                                const int* __restrict__ target, short* __restrict__ X) {
    int m = blockIdx.x;          // 0..M_PAD-1
    int e = threadIdx.x * 4;     // 0..1020
    short4v o;
    if (m >= M_REAL) {
        o = (short4v){0, 0, 0, 0};
    } else {
        int t = m >> 4, b = m & 15;
        float4 v;
        if (e < E_) {
            int tok = target[b * L_ + t];
            v = *(const float4*)(emb + (size_t)tok * E_ + e);
        } else {
            v = *(const float4*)(latent + (size_t)b * D_ + (e - E_));
        }
        o = (short4v){ f2bf(v.x), f2bf(v.y), f2bf(v.z), f2bf(v.w) };
    }
    *(short4v*)(X + (size_t)m * K_ + e) = o;
}

// ---------------------------------------------------------------------------
// bf16 MFMA GEMM: C[M,N] = A[M,K] * Bt[N,K]^T  (m97 structure: 128x128 tile,
// BK=32, global_load_lds width16, 2x2 waves x 4x4 16x16x32 frags)
// mode 0: out[m*N+n] = acc + bias1[n] + bias2[n]          (pre-gates)
// mode 1: out[b*L*V + (t+1)*V + n] = acc + bias1[n], m=t*16+b  (logits)
// ---------------------------------------------------------------------------
__global__ __launch_bounds__(256) void gemm_bt_kernel(
    const short* __restrict__ A, const short* __restrict__ Bt,
    float* __restrict__ out, const float* __restrict__ bias1,
    const float* __restrict__ bias2, int M_real, int N, int K, int mode) {
    __shared__ short As[128 * 32];
    __shared__ short Bs[128 * 32];
    const int tid  = threadIdx.x;
    const int w    = tid >> 6;
    const int lane = tid & 63;
    const int quad = lane >> 4;
    const int l16  = lane & 15;
    const int n0   = blockIdx.x * 128;
    const int m0   = blockIdx.y * 128;
    const int wm   = w >> 1, wn = w & 1;

    f32x4 acc[4][4];
#pragma unroll
    for (int i = 0; i < 4; ++i)
#pragma unroll
        for (int j = 0; j < 4; ++j) acc[i][j] = (f32x4){0.f, 0.f, 0.f, 0.f};

    const int srow = lane >> 2;        // staging row within 16-row segment
    const int skel = (lane & 3) * 8;   // staging k-element offset

    const int s0 = w, s1 = w + 4;      // this wave's two LDS segments
    for (int kk = 0; kk < K; kk += 32) {
        gl_lds16(A  + (size_t)(m0 + s0 * 16 + srow) * K + kk + skel, As + s0 * 512);
        gl_lds16(A  + (size_t)(m0 + s1 * 16 + srow) * K + kk + skel, As + s1 * 512);
        gl_lds16(Bt + (size_t)(n0 + s0 * 16 + srow) * K + kk + skel, Bs + s0 * 512);
        gl_lds16(Bt + (size_t)(n0 + s1 * 16 + srow) * K + kk + skel, Bs + s1 * 512);
        __syncthreads();
        short8 af[4], bf[4];
#pragma unroll
        for (int i = 0; i < 4; ++i)
            af[i] = *(const short8*)(As + (wm * 64 + i * 16 + l16) * 32 + quad * 8);
#pragma unroll
        for (int j = 0; j < 4; ++j)
            bf[j] = *(const short8*)(Bs + (wn * 64 + j * 16 + l16) * 32 + quad * 8);
#pragma unroll
        for (int i = 0; i < 4; ++i)
#pragma unroll
            for (int j = 0; j < 4; ++j)
                acc[i][j] = __builtin_amdgcn_mfma_f32_16x16x32_bf16(af[i], bf[j], acc[i][j], 0, 0, 0);
        __syncthreads();
    }

#pragma unroll
    for (int i = 0; i < 4; ++i) {
#pragma unroll
        for (int j = 0; j < 4; ++j) {
            const int mbase = m0 + wm * 64 + i * 16 + quad * 4;
            const int n     = n0 + wn * 64 + j * 16 + l16;
#pragma unroll
            for (int r = 0; r < 4; ++r) {
                const int m = mbase + r;
                if (m < M_real) {
                    float v = acc[i][j][r];
                    if (mode == 0) {
                        out[(size_t)m * N + n] = v + bias1[n] + bias2[n];
                    } else {
                        const int t = m >> 4, b = m & 15;
                        out[(size_t)b * ((size_t)L_ * V_) + (size_t)(t + 1) * V_ + n] = v + bias1[n];
                    }
                }
            }
        }
    }
}

// ---------------------------------------------------------------------------
// persistent LSTM recurrence: 64 blocks x 256 thr. Block p owns h-cols
// [p*16, p*16+16). Wave w computes gate w's 16x16 tile (K=1024) with its
// W_hh slice preloaded into 128 VGPRs. Per-step sync: relaxed agent-scope
// atomic h-stores (LLC-coherent, no fence) + s_waitcnt vmcnt(0) drain +
// per-block flag store; readers poll all 64 flags with one coalesced
// 64-lane atomic load per iteration. No RMW contention, no buffer_wbl2.
// ---------------------------------------------------------------------------
__global__ __launch_bounds__(256) void lstm_recur_kernel(
    const short* __restrict__ Whh,   // bf16 (4096 x 1024) row-major
    const float* __restrict__ xg,    // (M_PAD x 4096) fp32 precomputed gates
    short* __restrict__ Hall,        // bf16 (M_PAD+16 x 1024); row s*16+b = h_{s-1}[b]
    unsigned* flags) {               // 64 per-block progress counters
    __shared__ float gl[1024];
    const int tid  = threadIdx.x;
    const int w    = tid >> 6;
    const int lane = tid & 63;
    const int quad = lane >> 4;
    const int l16  = lane & 15;
    const int p    = blockIdx.x;     // 0..63

    // preload W_hh fragments: wave w, gate w, rows w*1024 + p*16 + l16
    const short* Brow = Whh + (size_t)(w * H_ + p * 16 + l16) * K_ + quad * 8;
    short8 breg[32];
#pragma unroll
    for (int ks = 0; ks < 32; ++ks) breg[ks] = *(const short8*)(Brow + ks * 32);

    const int b  = tid >> 4;   // epilogue mapping: thread owns (b, jc)
    const int jc = tid & 15;
    float c = 0.0f;
    unsigned* hall_u32 = (unsigned*)Hall;

    for (int t = 0; t < T_; ++t) {
        // issue xg loads early: independent of the flag poll, overlaps its latency
        const float* xgp = xg + (size_t)(t * 16 + b) * G4_ + p * 16 + jc;
        float x_i = xgp[0];
        float x_f = xgp[1024];
        float x_g = xgp[2048];
        float x_o = xgp[3072];

        // wait until every block has published h_{t-1} (flags[p] >= t)
        if (tid < 64) {
            while (__hip_atomic_load(&flags[tid], __ATOMIC_RELAXED,
                                     __HIP_MEMORY_SCOPE_AGENT) < (unsigned)t) {
                __builtin_amdgcn_s_sleep(1);
            }
        }
        __syncthreads();

        const short* Arow = Hall + (size_t)(t * 16 + l16) * K_ + quad * 8;
        f32x4 a0 = (f32x4){0.f,0.f,0.f,0.f}, a1 = a0, a2 = a0, a3 = a0;
#pragma unroll
        for (int ks = 0; ks < 32; ks += 4) {
            short8 f0 = *(const short8*)(Arow + (ks + 0) * 32);
            short8 f1 = *(const short8*)(Arow + (ks + 1) * 32);
            short8 f2 = *(const short8*)(Arow + (ks + 2) * 32);
            short8 f3 = *(const short8*)(Arow + (ks + 3) * 32);
            a0 = __builtin_amdgcn_mfma_f32_16x16x32_bf16(f0, breg[ks + 0], a0, 0, 0, 0);
            a1 = __builtin_amdgcn_mfma_f32_16x16x32_bf16(f1, breg[ks + 1], a1, 0, 0, 0);
            a2 = __builtin_amdgcn_mfma_f32_16x16x32_bf16(f2, breg[ks + 2], a2, 0, 0, 0);
            a3 = __builtin_amdgcn_mfma_f32_16x16x32_bf16(f3, breg[ks + 3], a3, 0, 0, 0);
        }
        f32x4 g = (a0 + a1) + (a2 + a3);
#pragma unroll
        for (int r = 0; r < 4; ++r) gl[w * 256 + (quad * 4 + r) * 16 + l16] = g[r];
        __syncthreads();

        float gi = gl[tid]       + x_i;
        float gf = gl[256 + tid] + x_f;
        float gg = gl[512 + tid] + x_g;
        float go = gl[768 + tid] + x_o;
        float iv = sigm(gi), fv = sigm(gf), gv = tanhf(gg), ov = sigm(go);
        c = fv * c + iv * gv;
        float h = ov * tanhf(c);

        // publish h: pack 2 bf16 per u32, relaxed agent-scope store (LLC-coherent)
        unsigned hb = (unsigned)(unsigned short)f2bf(h);
        unsigned nb = __shfl_xor(hb, 1);
        if ((jc & 1) == 0) {
            unsigned packed = hb | (nb << 16);   // low half = even col
            unsigned* dst = hall_u32 +
                ((size_t)((t + 1) * 16 + b) * K_ + (size_t)(p * 16 + jc)) / 2;
            __hip_atomic_store(dst, packed, __ATOMIC_RELAXED, __HIP_MEMORY_SCOPE_AGENT);
        }
        // drain this wave's stores to the coherence point, then block-barrier,
        // then one flag store announces "block p finished step t"
        __asm__ volatile("s_waitcnt vmcnt(0)" ::: "memory");
        __syncthreads();
        if (tid == 0) {
            __hip_atomic_store(&flags[p], (unsigned)(t + 1), __ATOMIC_RELAXED,
                               __HIP_MEMORY_SCOPE_AGENT);
        }
        // NOTE: no trailing __syncthreads needed — next iteration's poll +
        // __syncthreads provides the rendezvous.
    }
}

// ---------------------------------------------------------------------------
// zero out[:, 0, :]
// ---------------------------------------------------------------------------
__global__ void zero_t0_kernel(float* __restrict__ out) {
    int i = blockIdx.x * blockDim.x + threadIdx.x;
    if (i < B_ * V_) {
        int b = i / V_, v = i - b * V_;
        out[(size_t)b * ((size_t)L_ * V_) + v] = 0.f;
    }
}

extern "C" void kernel_launch(void* const* d_in, const int* in_sizes, int n_in,
                              void* d_out, int out_size, void* d_ws, size_t ws_size,
                              hipStream_t stream) {
    const float* latent = (const float*)d_in[0];
    const float* emb    = (const float*)d_in[1];
    const float* W_ih   = (const float*)d_in[2];
    const float* W_hh   = (const float*)d_in[3];
    const float* b_ih   = (const float*)d_in[4];
    const float* b_hh   = (const float*)d_in[5];
    const float* fc_w   = (const float*)d_in[6];
    const float* fc_b   = (const float*)d_in[7];
    const int*   target = (const int*)d_in[8];
    float* out = (float*)d_out;

    char* ws = (char*)d_ws;
    unsigned* flags = (unsigned*)ws;
    size_t off = 256;
    short* Wih_b = (short*)(ws + off); off += (size_t)G4_ * K_ * 2;          // 8 MB
    short* Whh_b = (short*)(ws + off); off += (size_t)G4_ * K_ * 2;          // 8 MB
    short* fcw_b = (short*)(ws + off); off += (size_t)V_ * K_ * 2;           // 62.5 MB
    short* X_b   = (short*)(ws + off); off += (size_t)M_PAD * K_ * 2;        // 4 MB
    short* Hall  = (short*)(ws + off); off += (size_t)(M_PAD + 16) * K_ * 2; // 4 MB
    float* xg    = (float*)(ws + off); off += (size_t)M_PAD * G4_ * 4;       // 32 MB
    (void)ws_size; (void)in_sizes; (void)n_in; (void)out_size;

    // 0) init Hall zeros + flags
    init_kernel<<<512, 256, 0, stream>>>((unsigned*)Hall, flags);
    // 1) weight converts fp32->bf16
    cvt_bf16_kernel<<<(G4_ * K_ / 4 + 255) / 256, 256, 0, stream>>>(W_ih, Wih_b, G4_ * K_ / 4);
    cvt_bf16_kernel<<<(G4_ * K_ / 4 + 255) / 256, 256, 0, stream>>>(W_hh, Whh_b, G4_ * K_ / 4);
    cvt_bf16_kernel<<<(V_ * K_ / 4 + 255) / 256, 256, 0, stream>>>(fc_w, fcw_b, V_ * K_ / 4);
    // 2) gather X = [emb[tok], latent] in bf16
    gather_x_kernel<<<M_PAD, 256, 0, stream>>>(emb, latent, target, X_b);
    // 3) pre-gates: xg = X @ W_ih^T + (b_ih + b_hh)
    gemm_bt_kernel<<<dim3(G4_ / 128, M_PAD / 128), 256, 0, stream>>>(
        X_b, Wih_b, xg, b_ih, b_hh, M_PAD, G4_, K_, 0);
    // 4) recurrence (persistent, 127 steps, flag-based sync)
    lstm_recur_kernel<<<64, 256, 0, stream>>>(Whh_b, xg, Hall, flags);
    // 5) logits = Hall[1..127] @ fc_w^T + fc_b -> out[:, 1:, :]
    gemm_bt_kernel<<<dim3(V_ / 128, M_PAD / 128), 256, 0, stream>>>(
        Hall + (size_t)16 * K_, fcw_b, out, fc_b, nullptr, M_REAL, V_, K_, 1);
    // 6) out[:, 0, :] = 0
    zero_t0_kernel<<<(B_ * V_ + 255) / 256, 256, 0, stream>>>(out);
}